// Round 12
// baseline (799.089 us; speedup 1.0000x reference)
//
#include <hip/hip_runtime.h>
#include <hip/hip_bf16.h>
#include <math.h>

#define H 128
#define RS 136    // LDS row stride in shorts (128 + 8 pad; keeps ds_read_b128 16B-aligned)
#define BSH 9     // bin shift: 512 nodes per bin
#define BINW 512
#define BCAP 11264  // max edges/bin for LDS sort
#define BSLOT 12288 // per-bin slot capacity in temp (direct scatter)
#define KEDGE 4096  // edges per partition block
#define EPT 16      // edges per thread (KEDGE/256)
#define MAXBINS 1024

typedef __attribute__((ext_vector_type(8))) short short8;
typedef __attribute__((ext_vector_type(4))) short short4v;
typedef __attribute__((ext_vector_type(2))) short short2v;
typedef __attribute__((ext_vector_type(4))) float f32x4;

// fp32 -> bf16 (RNE); values here are finite (no NaN handling needed)
__device__ __forceinline__ short f2bf(float f) {
    unsigned u = __float_as_uint(f);
    u += 0x7fff + ((u >> 16) & 1);
    return (short)(u >> 16);
}
__device__ __forceinline__ float bf2f(short h) {
    return __uint_as_float(((unsigned)(unsigned short)h) << 16);
}

// ---------------- CSR build (direct slot scatter -> scan -> in-bin sort+rowptr) ----------
// Node space concatenated: [NP(isa) | NG(rel) | NP(rev)].

__global__ __launch_bounds__(256) void bin_scatter_kernel(
    const int* __restrict__ e0, int E0, const int* __restrict__ e1, int E1,
    const int* __restrict__ e2, int E2, int* __restrict__ bin_cur,
    int* __restrict__ temp, int NPn, int NGn, int nbins, int E_tot) {
    __shared__ int hist[MAXBINS];
    __shared__ int cur[MAXBINS];
    int t = threadIdx.x;
    for (int i = t; i < nbins; i += 256) hist[i] = 0;
    __syncthreads();
    int vals[EPT], bins[EPT];
    int base_e = blockIdx.x * KEDGE;
#pragma unroll
    for (int j = 0; j < EPT; ++j) {
        int g = base_e + j * 256 + t;      // coalesced within each j-step
        int b = -1, v = 0;
        if (g < E_tot) {
            const int* ed; int E, lo, nbase;
            if (g < E0) { ed = e0; E = E0; lo = g; nbase = 0; }
            else if (g < E0 + E1) { ed = e1; E = E1; lo = g - E0; nbase = NPn; }
            else { ed = e2; E = E2; lo = g - E0 - E1; nbase = NPn + NGn; }
            int src = ed[lo];
            int gdst = nbase + ed[E + lo];
            v = src | ((gdst & (BINW - 1)) << 16);
            b = gdst >> BSH;
            atomicAdd(&hist[b], 1);        // LDS atomic
        }
        vals[j] = v;
        bins[j] = b;
    }
    __syncthreads();
    for (int i = t; i < nbins; i += 256) {
        int h = hist[i];
        cur[i] = h ? atomicAdd(&bin_cur[i * 16], h) : 0;   // reserve run (local slot base)
    }
    __syncthreads();
#pragma unroll
    for (int j = 0; j < EPT; ++j) {
        if (bins[j] >= 0) {
            int p = atomicAdd(&cur[bins[j]], 1);           // LDS atomic -> local slot
            if (p < BSLOT) temp[(size_t)bins[j] * BSLOT + p] = vals[j];
        }
    }
}

__global__ __launch_bounds__(1024) void scan_bins(const int* __restrict__ bin_cur, int nbins,
                                                  int* __restrict__ bin_base) {
    __shared__ int sh[1024];
    int t = threadIdx.x;
    int v = 0;
    if (t < nbins) { v = bin_cur[t * 16]; if (v > BSLOT) v = BSLOT; }
    sh[t] = v;
    __syncthreads();
    for (int off = 1; off < 1024; off <<= 1) {
        int u = (t >= off) ? sh[t - off] : 0;
        __syncthreads();
        sh[t] += u;
        __syncthreads();
    }
    if (t < nbins) bin_base[t] = sh[t] - v;    // exclusive
    if (t == nbins - 1) bin_base[nbins] = sh[t];
}

__global__ __launch_bounds__(256) void bin_sort_kernel(
    const int* __restrict__ bin_base, const int* __restrict__ temp,
    int* __restrict__ col, int* __restrict__ rowptr, int n_tot, int nbins) {
    __shared__ int srt[BCAP];
    __shared__ int cur[BINW];
    __shared__ int pfx[BINW];
    __shared__ int red[256];
    int b = blockIdx.x;
    int start = b << BSH;
    int nodes = n_tot - start; if (nodes > BINW) nodes = BINW;
    int t = threadIdx.x;
    int base = bin_base[b];
    int count = bin_base[b + 1] - base;
    const int* __restrict__ tb = temp + (size_t)b * BSLOT;
    for (int i = t; i < BINW; i += 256) cur[i] = 0;
    __syncthreads();
    for (int i = t; i < count; i += 256)
        atomicAdd(&cur[(tb[i] >> 16) & (BINW - 1)], 1);
    __syncthreads();
    int a0 = cur[2 * t], a1 = cur[2 * t + 1];
    red[t] = a0 + a1;
    __syncthreads();
    for (int off = 1; off < 256; off <<= 1) {
        int u = (t >= off) ? red[t - off] : 0;
        __syncthreads();
        red[t] += u;
        __syncthreads();
    }
    int excl = red[t] - (a0 + a1);
    pfx[2 * t] = excl;
    pfx[2 * t + 1] = excl + a0;
    __syncthreads();
    for (int i = t; i < nodes; i += 256) rowptr[start + i] = base + pfx[i];
    if (b == nbins - 1 && t == 0) rowptr[n_tot] = base + count;
    for (int i = t; i < BINW; i += 256) cur[i] = pfx[i];
    __syncthreads();
    if (count <= BCAP) {
        for (int i = t; i < count; i += 256) {
            int v = tb[i];
            int p = atomicAdd(&cur[(v >> 16) & (BINW - 1)], 1);
            srt[p] = v & 0xFFFF;
        }
        __syncthreads();
        for (int i = t; i < count; i += 256) col[base + i] = srt[i];
    } else {  // fallback (not expected): direct global scatter
        for (int i = t; i < count; i += 256) {
            int v = tb[i];
            int p = atomicAdd(&cur[(v >> 16) & (BINW - 1)], 1);
            col[base + p] = v & 0xFFFF;
        }
    }
}

// ---------------- W pack: fp32 [k][n] -> MFMA B-fragment order, split bf16 hi/lo ----------------

struct WSrc { const float* a[15]; const float* b[15]; };

__global__ __launch_bounds__(256) void pack_w_kernel(WSrc src, short* __restrict__ whi,
                                                     short* __restrict__ wlo) {
    int idx = blockIdx.x * 256 + threadIdx.x;   // (mat, kc, ct, lane)
    if (idx >= 15 * 4 * 8 * 64) return;
    int lane = idx & 63;
    int ct = (idx >> 6) & 7;
    int kc = (idx >> 9) & 3;
    int mat = idx >> 11;
    const float* A = src.a[mat];
    const float* Bp = src.b[mat];
    int n = ct * 16 + (lane & 15);
    int kbase = kc * 32 + (lane >> 4) * 8;
    size_t o = (size_t)idx * 8;
    for (int j = 0; j < 8; ++j) {
        float v = A[(size_t)(kbase + j) * H + n];
        if (Bp) v += Bp[(size_t)(kbase + j) * H + n];
        short h = f2bf(v);
        whi[o + j] = h;
        wlo[o + j] = f2bf(v - bf2f(h));
    }
}

// ---------------- fp32 -> split-bf16 hi/lo planes (layer-0 inputs, both matrices) ----------
// Same f2bf split as the old GEMM fp32 stage -> layer-0 copy operands bit-identical.

__global__ __launch_bounds__(256) void split32_kernel(
    const float* __restrict__ xa, int n4a, const float* __restrict__ xb, int n4b,
    short* __restrict__ ha, short* __restrict__ la,
    short* __restrict__ hb, short* __restrict__ lb) {
    int i = blockIdx.x * 256 + threadIdx.x;
    const float* x; short* hp; short* lp; size_t o;
    if (i < n4a) { x = xa; hp = ha; lp = la; o = (size_t)i * 4; }
    else if (i < n4a + n4b) { x = xb; hp = hb; lp = lb; o = (size_t)(i - n4a) * 4; }
    else return;
    f32x4 v = *(const f32x4*)&x[o];
    short4v h, l;
#pragma unroll
    for (int k = 0; k < 4; ++k) {
        h[k] = f2bf(v[k]);
        l[k] = f2bf(v[k] - bf2f(h[k]));
    }
    *(short4v*)&hp[o] = h;
    *(short4v*)&lp[o] = l;
}

// ---------------- scalar-base split-bf16 segment mean ----------------
// R5's proven index path VERBATIM (contiguous col[e+i] + readfirstlane -> merged wide
// s_loads); per index, payload is now TWO 4B loads (hi & lo planes, both saddr+voffset):
// same bytes per edge as the old fp16 row, 32 loads in flight per chunk (2x MLP).
// Operand value = bf2f(hi)+bf2f(lo) ~= exact fp32 (more precise than fp16 mirror).

__device__ __forceinline__ float2 seg16hl(const short* __restrict__ hi,
                                          const short* __restrict__ lo,
                                          const int* __restrict__ rowptr,
                                          const int* __restrict__ col,
                                          int rb, int voff) {
    int beg = rowptr[rb], end = rowptr[rb + 1];
    float ax0 = 0.f, ax1 = 0.f, ax2 = 0.f, ax3 = 0.f;
    float ay0 = 0.f, ay1 = 0.f, ay2 = 0.f, ay3 = 0.f;
    int e = beg;
    while (e + 16 <= end) {               // uniform loop control
        short2v h[16], l[16];
#pragma unroll
        for (int i = 0; i < 16; ++i) {
            int si = __builtin_amdgcn_readfirstlane(col[e + i]);   // SGPR row index
            h[i] = *(const short2v*)(hi + (size_t)si * H + voff);  // saddr + voffset
            l[i] = *(const short2v*)(lo + (size_t)si * H + voff);
        }
#pragma unroll
        for (int i = 0; i < 16; i += 4) {
            ax0 += bf2f(h[i + 0][0]) + bf2f(l[i + 0][0]); ay0 += bf2f(h[i + 0][1]) + bf2f(l[i + 0][1]);
            ax1 += bf2f(h[i + 1][0]) + bf2f(l[i + 1][0]); ay1 += bf2f(h[i + 1][1]) + bf2f(l[i + 1][1]);
            ax2 += bf2f(h[i + 2][0]) + bf2f(l[i + 2][0]); ay2 += bf2f(h[i + 2][1]) + bf2f(l[i + 2][1]);
            ax3 += bf2f(h[i + 3][0]) + bf2f(l[i + 3][0]); ay3 += bf2f(h[i + 3][1]) + bf2f(l[i + 3][1]);
        }
        e += 16;
    }
    int rem = end - e;
    if (rem > 8) {                        // 9..15 left: one 16-wide masked tail
        int last = end - 1;
        short2v h[16], l[16];
#pragma unroll
        for (int i = 0; i < 16; ++i) {
            int p = e + i; if (p > last) p = last;
            int si = __builtin_amdgcn_readfirstlane(col[p]);
            h[i] = *(const short2v*)(hi + (size_t)si * H + voff);
            l[i] = *(const short2v*)(lo + (size_t)si * H + voff);
        }
#pragma unroll
        for (int i = 0; i < 16; ++i) {
            float m = (i < rem) ? 1.0f : 0.0f;
            float fx = bf2f(h[i][0]) + bf2f(l[i][0]);
            float fy = bf2f(h[i][1]) + bf2f(l[i][1]);
            if ((i & 3) == 0) { ax0 = fmaf(fx, m, ax0); ay0 = fmaf(fy, m, ay0); }
            else if ((i & 3) == 1) { ax1 = fmaf(fx, m, ax1); ay1 = fmaf(fy, m, ay1); }
            else if ((i & 3) == 2) { ax2 = fmaf(fx, m, ax2); ay2 = fmaf(fy, m, ay2); }
            else { ax3 = fmaf(fx, m, ax3); ay3 = fmaf(fy, m, ay3); }
        }
    } else if (rem > 0) {                 // 1..8 left: one 8-wide masked tail
        int last = end - 1;
        short2v h[8], l[8];
#pragma unroll
        for (int i = 0; i < 8; ++i) {
            int p = e + i; if (p > last) p = last;
            int si = __builtin_amdgcn_readfirstlane(col[p]);
            h[i] = *(const short2v*)(hi + (size_t)si * H + voff);
            l[i] = *(const short2v*)(lo + (size_t)si * H + voff);
        }
#pragma unroll
        for (int i = 0; i < 8; ++i) {
            float m = (i < rem) ? 1.0f : 0.0f;
            float fx = bf2f(h[i][0]) + bf2f(l[i][0]);
            float fy = bf2f(h[i][1]) + bf2f(l[i][1]);
            if ((i & 3) == 0) { ax0 = fmaf(fx, m, ax0); ay0 = fmaf(fy, m, ay0); }
            else if ((i & 3) == 1) { ax1 = fmaf(fx, m, ax1); ay1 = fmaf(fy, m, ay1); }
            else if ((i & 3) == 2) { ax2 = fmaf(fx, m, ax2); ay2 = fmaf(fy, m, ay2); }
            else { ax3 = fmaf(fx, m, ax3); ay3 = fmaf(fy, m, ay3); }
        }
    }
    float sx = (ax0 + ax1) + (ax2 + ax3);
    float sy = (ay0 + ay1) + (ay2 + ay3);
    int c = end - beg; if (c < 1) c = 1;
    float inv = 1.0f / (float)c;
    return (float2){sx * inv, sy * inv};
}

// ---------------- fused SAGE layer body: 8-wave blocks, plane-only dataflow ----------------
// All activations live as split-bf16 hi/lo planes (ping-pong sets). Gather terms read
// both planes of the READ set; copy terms stream the read set's own rows; epilogue writes
// ONLY hi/lo to the WRITE set (fp16 mirror eliminated: -2B/elem writes, no in-place
// hazards anywhere since read set != write set).

struct GTerm {
    const short* hi;
    const short* lo;
    int rbase;           // >=0: gather (rowptr base index); <0: copy own rows
};

template <int NIN>
__device__ __forceinline__ void layer_body(
    short* __restrict__ Ahi, short* __restrict__ Alo,
    GTerm t0, GTerm t1, GTerm t2,
    const int* __restrict__ rowptr, const int* __restrict__ col,
    const short* __restrict__ whi, const short* __restrict__ wlo,
    int mat0, int mat1, int mat2,
    const float* __restrict__ b0, const float* __restrict__ b1,
    short* __restrict__ ohi, short* __restrict__ olo,
    int n_rows, int relu, int bx) {
    const int tid = threadIdx.x;
    const int lane = tid & 63;
    const int wave = __builtin_amdgcn_readfirstlane(tid >> 6);   // 0..7
    const int r0 = bx * 64;
    const int ct0 = wave;              // one 16-col tile per wave
    const int m16 = lane & 15;
    const int acol = (lane >> 4) * 8;

    f32x4 acc[4];
#pragma unroll
    for (int mt = 0; mt < 4; ++mt) acc[mt] = (f32x4){0.f, 0.f, 0.f, 0.f};

    const GTerm terms[3] = {t0, t1, t2};
    const int marr[3] = {mat0, mat1, mat2};

#pragma unroll
    for (int m = 0; m < NIN; ++m) {
        const GTerm& T = terms[m];
        __syncthreads();
        if (T.rbase >= 0) {                 // gather-mean term: wave w owns rows 8w..8w+7
            int voff = lane * 2;
            for (int rr = 0; rr < 8; ++rr) {
                int lrow = wave * 8 + rr;
                int gr = r0 + lrow;
                if (gr >= n_rows) gr = n_rows - 1;     // dup row: harmless recompute
                float2 s = seg16hl(T.hi, T.lo, rowptr, col, T.rbase + gr, voff);
                short h0 = f2bf(s.x), h1 = f2bf(s.y);
                *(short2v*)&Ahi[lrow * RS + voff] = (short2v){h0, h1};
                *(short2v*)&Alo[lrow * RS + voff] =
                    (short2v){f2bf(s.x - bf2f(h0)), f2bf(s.y - bf2f(h1))};
            }
        } else {                            // pre-split planes: pure copy
#pragma unroll
            for (int i = 0; i < 4; ++i) {
                int f = tid + i * 512;
                int row = f >> 5;
                int c4 = (f & 31) * 4;
                int gr = r0 + row;
                if (gr >= n_rows) gr = n_rows - 1;
                size_t o = (size_t)gr * H + c4;
                *(short4v*)&Ahi[row * RS + c4] = *(const short4v*)&T.hi[o];
                *(short4v*)&Alo[row * RS + c4] = *(const short4v*)&T.lo[o];
            }
        }
        __syncthreads();
        const short* __restrict__ wh = whi + (size_t)marr[m] * (H * H);
        const short* __restrict__ wl = wlo + (size_t)marr[m] * (H * H);
        short8 bh[2], bl[2];
        {
            size_t f0 = ((size_t)ct0 * 64 + lane) * 8;
            bh[0] = *(const short8*)&wh[f0];
            bl[0] = *(const short8*)&wl[f0];
        }
#pragma unroll
        for (int kc = 0; kc < 4; ++kc) {
            if (kc < 3) {
                int nb = (kc + 1) & 1;
                size_t f = ((size_t)((kc + 1) * 8 + ct0) * 64 + lane) * 8;
                bh[nb] = *(const short8*)&wh[f];
                bl[nb] = *(const short8*)&wl[f];
            }
            int cb = kc & 1;
#pragma unroll
            for (int mt = 0; mt < 4; ++mt) {
                short8 ah = *(const short8*)&Ahi[(mt * 16 + m16) * RS + kc * 32 + acol];
                short8 al = *(const short8*)&Alo[(mt * 16 + m16) * RS + kc * 32 + acol];
                acc[mt] = __builtin_amdgcn_mfma_f32_16x16x32_bf16(ah, bh[cb], acc[mt], 0, 0, 0);
                acc[mt] = __builtin_amdgcn_mfma_f32_16x16x32_bf16(al, bh[cb], acc[mt], 0, 0, 0);
                acc[mt] = __builtin_amdgcn_mfma_f32_16x16x32_bf16(ah, bl[cb], acc[mt], 0, 0, 0);
            }
        }
    }

    const int rquad = (lane >> 4) * 4;
    const int ncol = lane & 15;
    {
        int n = ct0 * 16 + ncol;
        float bs = b0[n];
        if (b1) bs += b1[n];
#pragma unroll
        for (int mt = 0; mt < 4; ++mt) {
#pragma unroll
            for (int reg = 0; reg < 4; ++reg) {
                int gr = r0 + mt * 16 + rquad + reg;
                if (gr < n_rows) {
                    float v = acc[mt][reg] + bs;
                    if (relu) v = v > 0.f ? v : 0.01f * v;
                    size_t o = (size_t)gr * H + n;
                    short h = f2bf(v);
                    ohi[o] = h;
                    olo[o] = f2bf(v - bf2f(h));
                }
            }
        }
    }
}

// One launch per layer: blocks [0, nbp) = pheno path (3 terms), rest = gene path (2 terms).
// 512 threads (8 waves); launch_bounds(512,3) gives ~85 VGPR budget for the 32-deep
// h/l load window (no spill), 3 blocks/CU.
struct LayerArgs {
    GTerm p0, p1, p2, g0, g1;
    const int* rowptr; const int* col;
    const short* whi; const short* wlo;
    int pm0, pm1, pm2, gm0, gm1;
    const float* pb0; const float* pb1; const float* gb0;
    short* poh; short* pol; int np;
    short* goh; short* gol; int ng;
    int relu; int nbp;
};

__global__ __launch_bounds__(512, 3) void fused_layer(LayerArgs a) {
    __shared__ short Ahi[64 * RS];
    __shared__ short Alo[64 * RS];
    int bx = blockIdx.x;
    if (bx < a.nbp) {
        layer_body<3>(Ahi, Alo, a.p0, a.p1, a.p2, a.rowptr, a.col, a.whi, a.wlo,
                      a.pm0, a.pm1, a.pm2, a.pb0, a.pb1,
                      a.poh, a.pol, a.np, a.relu, bx);
    } else {
        layer_body<2>(Ahi, Alo, a.g0, a.g1, a.g1, a.rowptr, a.col, a.whi, a.wlo,
                      a.gm0, a.gm1, 0, a.gb0, nullptr,
                      a.goh, a.gol, a.ng, a.relu, bx - a.nbp);
    }
}

// ---------------- edge decoder: sigmoid(dot(xp[i], xg[j])) on split-bf16 planes ----------

__global__ __launch_bounds__(256) void scores_kernel(
    const short* __restrict__ ph, const short* __restrict__ pl,
    const short* __restrict__ gh, const short* __restrict__ gl,
    const int* __restrict__ eli, int E, float* __restrict__ out) {
    int lane16 = threadIdx.x & 15;
    int sub = threadIdx.x >> 4;     // 16 edges per block
    int e = blockIdx.x * 16 + sub;
    if (e >= E) return;
    int ip = eli[e];
    int ig = eli[E + e];
    size_t po = (size_t)ip * H + lane16 * 8;
    size_t go = (size_t)ig * H + lane16 * 8;
    short8 ah = *(const short8*)&ph[po];
    short8 al = *(const short8*)&pl[po];
    short8 bh = *(const short8*)&gh[go];
    short8 bl = *(const short8*)&gl[go];
    float s = 0.f;
#pragma unroll
    for (int k = 0; k < 8; ++k)
        s += (bf2f(ah[k]) + bf2f(al[k])) * (bf2f(bh[k]) + bf2f(bl[k]));
#pragma unroll
    for (int off = 8; off; off >>= 1) s += __shfl_xor(s, off, 16);
    if (lane16 == 0) out[e] = 1.0f / (1.0f + expf(-s));
}

// ---------------- host ----------------

extern "C" void kernel_launch(void* const* d_in, const int* in_sizes, int n_in,
                              void* d_out, int out_size, void* d_ws, size_t ws_size,
                              hipStream_t stream) {
    const float* x_pheno = (const float*)d_in[0];
    const float* x_gene  = (const float*)d_in[1];
    const float* Wl_isa  = (const float*)d_in[2];
    const float* bl_isa  = (const float*)d_in[3];
    const float* Wr_isa  = (const float*)d_in[4];
    const float* Wl_rel  = (const float*)d_in[5];
    const float* bl_rel  = (const float*)d_in[6];
    const float* Wr_rel  = (const float*)d_in[7];
    const float* Wl_rev  = (const float*)d_in[8];
    const float* bl_rev  = (const float*)d_in[9];
    const float* Wr_rev  = (const float*)d_in[10];
    const int* e_isa = (const int*)d_in[11];
    const int* e_rel = (const int*)d_in[12];
    const int* e_rev = (const int*)d_in[13];
    const int* e_lbl = (const int*)d_in[14];
    const int E_isa = in_sizes[11] / 2;
    const int E_rel = in_sizes[12] / 2;
    const int E_rev = in_sizes[13] / 2;
    const int E_lbl = in_sizes[14] / 2;
    const int NP = in_sizes[0] / H;
    const int NG = in_sizes[1] / H;
    const int n_tot = NP + NG + NP;
    const int E_tot = E_isa + E_rel + E_rev;
    const int nbins = (n_tot + BINW - 1) / BINW;

    char* ws = (char*)d_ws;
    auto alloc = [&](size_t bytes) -> char* {
        char* p = ws;
        ws += (bytes + 255) & ~(size_t)255;
        return p;
    };
    int* rowptr  = (int*)alloc((size_t)(n_tot + 1) * 4);
    int* col     = (int*)alloc((size_t)E_tot * 4 + 64);   // +64B slack
    int* temp    = (int*)alloc((size_t)nbins * BSLOT * 4);
    int* bin_cur = (int*)alloc((size_t)nbins * 16 * 4);   // 64B-strided counters
    int* bin_base= (int*)alloc((size_t)(nbins + 1) * 4);
    short* whi = (short*)alloc((size_t)15 * H * H * sizeof(short));
    short* wlo = (short*)alloc((size_t)15 * H * H * sizeof(short));
    short *ph[2], *pl[2], *gh[2], *gl[2];
    for (int s = 0; s < 2; ++s) {
        ph[s] = (short*)alloc((size_t)NP * H * sizeof(short));
        pl[s] = (short*)alloc((size_t)NP * H * sizeof(short));
        gh[s] = (short*)alloc((size_t)NG * H * sizeof(short));
        gl[s] = (short*)alloc((size_t)NG * H * sizeof(short));
    }

    // ---- CSR build (every call; ws is re-poisoned by the harness) ----
    hipMemsetAsync(bin_cur, 0, (size_t)nbins * 16 * 4, stream);
    bin_scatter_kernel<<<(E_tot + KEDGE - 1) / KEDGE, 256, 0, stream>>>(
        e_isa, E_isa, e_rel, E_rel, e_rev, E_rev, bin_cur, temp, NP, NG, nbins, E_tot);
    scan_bins<<<1, 1024, 0, stream>>>(bin_cur, nbins, bin_base);
    bin_sort_kernel<<<nbins, 256, 0, stream>>>(bin_base, temp, col, rowptr, n_tot, nbins);

    // ---- W pack: per layer slots {Wl_isa, Wl_rev, Wsum=Wr_isa+Wr_rev, Wl_rel, Wr_rel} ----
    WSrc src;
    for (int l = 0; l < 3; ++l) {
        src.a[l * 5 + 0] = Wl_isa + (size_t)l * H * H;  src.b[l * 5 + 0] = nullptr;
        src.a[l * 5 + 1] = Wl_rev + (size_t)l * H * H;  src.b[l * 5 + 1] = nullptr;
        src.a[l * 5 + 2] = Wr_isa + (size_t)l * H * H;  src.b[l * 5 + 2] = Wr_rev + (size_t)l * H * H;
        src.a[l * 5 + 3] = Wl_rel + (size_t)l * H * H;  src.b[l * 5 + 3] = nullptr;
        src.a[l * 5 + 4] = Wr_rel + (size_t)l * H * H;  src.b[l * 5 + 4] = nullptr;
    }
    pack_w_kernel<<<(15 * 4 * 8 * 64 + 255) / 256, 256, 0, stream>>>(src, whi, wlo);

    // ---- layer-0 split-bf16 planes of the inputs (set 0) ----
    split32_kernel<<<((NP + NG) * 32 + 255) / 256, 256, 0, stream>>>(
        x_pheno, NP * 32, x_gene, NG * 32, ph[0], pl[0], gh[0], gl[0]);

    // ---- 3 fused layers (read set rs = l&1, write set rs^1; no in-place anywhere) ----
    const int nbp = (NP + 63) / 64, nbg = (NG + 63) / 64;
    for (int l = 0; l < 3; ++l) {
        int rs = l & 1;
        int wsid = rs ^ 1;
        LayerArgs a;
        a.p0 = GTerm{ph[rs], pl[rs], 0};            // isa-mean over pheno
        a.p1 = GTerm{gh[rs], gl[rs], NP + NG};      // rev-mean over gene
        a.p2 = GTerm{ph[rs], pl[rs], -1};           // copy own pheno rows
        a.g0 = GTerm{ph[rs], pl[rs], NP};           // rel-mean over pheno
        a.g1 = GTerm{gh[rs], gl[rs], -1};           // copy own gene rows
        a.rowptr = rowptr; a.col = col; a.whi = whi; a.wlo = wlo;
        a.pm0 = l * 5 + 0; a.pm1 = l * 5 + 1; a.pm2 = l * 5 + 2;
        a.gm0 = l * 5 + 3; a.gm1 = l * 5 + 4;
        a.pb0 = bl_isa + (size_t)l * H; a.pb1 = bl_rev + (size_t)l * H;
        a.gb0 = bl_rel + (size_t)l * H;
        a.poh = ph[wsid]; a.pol = pl[wsid]; a.np = NP;
        a.goh = gh[wsid]; a.gol = gl[wsid]; a.ng = NG;
        a.relu = (l < 2) ? 1 : 0; a.nbp = nbp;
        fused_layer<<<nbp + nbg, 512, 0, stream>>>(a);
    }

    // ---- decoder (layer 2 wrote set 1) ----
    scores_kernel<<<(E_lbl + 15) / 16, 256, 0, stream>>>(
        ph[1], pl[1], gh[1], gl[1], e_lbl, E_lbl, (float*)d_out);
}

// Round 13
// 591.092 us; speedup vs baseline: 1.3519x; 1.3519x over previous
//
#include <hip/hip_runtime.h>
#include <hip/hip_bf16.h>
#include <math.h>

#define H 128
#define RS 136    // LDS row stride in shorts (128 + 8 pad; keeps ds_read_b128 16B-aligned)
#define BSH 9     // bin shift: 512 nodes per bin
#define BINW 512
#define BCAP 11264  // max edges/bin for LDS sort
#define BSLOT 12288 // per-bin slot capacity in temp (direct scatter)
#define KEDGE 4096  // edges per partition block
#define EPT 16      // edges per thread (KEDGE/256)
#define MAXBINS 1024

typedef __attribute__((ext_vector_type(8))) short short8;
typedef __attribute__((ext_vector_type(4))) short short4v;
typedef __attribute__((ext_vector_type(2))) short short2v;
typedef __attribute__((ext_vector_type(4))) float f32x4;
typedef __attribute__((ext_vector_type(2))) _Float16 half2v;
typedef __attribute__((ext_vector_type(4))) _Float16 half4v;
typedef __attribute__((ext_vector_type(8))) _Float16 half8v;

// fp32 -> bf16 (RNE); values here are finite (no NaN handling needed)
__device__ __forceinline__ short f2bf(float f) {
    unsigned u = __float_as_uint(f);
    u += 0x7fff + ((u >> 16) & 1);
    return (short)(u >> 16);
}
__device__ __forceinline__ float bf2f(short h) {
    return __uint_as_float(((unsigned)(unsigned short)h) << 16);
}

// ---------------- CSR build (direct slot scatter -> scan -> in-bin sort+rowptr) ----------
// Node space concatenated: [NP(isa) | NG(rel) | NP(rev)].

__global__ __launch_bounds__(256) void bin_scatter_kernel(
    const int* __restrict__ e0, int E0, const int* __restrict__ e1, int E1,
    const int* __restrict__ e2, int E2, int* __restrict__ bin_cur,
    int* __restrict__ temp, int NPn, int NGn, int nbins, int E_tot) {
    __shared__ int hist[MAXBINS];
    __shared__ int cur[MAXBINS];
    int t = threadIdx.x;
    for (int i = t; i < nbins; i += 256) hist[i] = 0;
    __syncthreads();
    int vals[EPT], bins[EPT];
    int base_e = blockIdx.x * KEDGE;
#pragma unroll
    for (int j = 0; j < EPT; ++j) {
        int g = base_e + j * 256 + t;      // coalesced within each j-step
        int b = -1, v = 0;
        if (g < E_tot) {
            const int* ed; int E, lo, nbase;
            if (g < E0) { ed = e0; E = E0; lo = g; nbase = 0; }
            else if (g < E0 + E1) { ed = e1; E = E1; lo = g - E0; nbase = NPn; }
            else { ed = e2; E = E2; lo = g - E0 - E1; nbase = NPn + NGn; }
            int src = ed[lo];
            int gdst = nbase + ed[E + lo];
            v = src | ((gdst & (BINW - 1)) << 16);
            b = gdst >> BSH;
            atomicAdd(&hist[b], 1);        // LDS atomic
        }
        vals[j] = v;
        bins[j] = b;
    }
    __syncthreads();
    for (int i = t; i < nbins; i += 256) {
        int h = hist[i];
        cur[i] = h ? atomicAdd(&bin_cur[i * 16], h) : 0;   // reserve run (local slot base)
    }
    __syncthreads();
#pragma unroll
    for (int j = 0; j < EPT; ++j) {
        if (bins[j] >= 0) {
            int p = atomicAdd(&cur[bins[j]], 1);           // LDS atomic -> local slot
            if (p < BSLOT) temp[(size_t)bins[j] * BSLOT + p] = vals[j];
        }
    }
}

__global__ __launch_bounds__(1024) void scan_bins(const int* __restrict__ bin_cur, int nbins,
                                                  int* __restrict__ bin_base) {
    __shared__ int sh[1024];
    int t = threadIdx.x;
    int v = 0;
    if (t < nbins) { v = bin_cur[t * 16]; if (v > BSLOT) v = BSLOT; }
    sh[t] = v;
    __syncthreads();
    for (int off = 1; off < 1024; off <<= 1) {
        int u = (t >= off) ? sh[t - off] : 0;
        __syncthreads();
        sh[t] += u;
        __syncthreads();
    }
    if (t < nbins) bin_base[t] = sh[t] - v;    // exclusive
    if (t == nbins - 1) bin_base[nbins] = sh[t];
}

__global__ __launch_bounds__(256) void bin_sort_kernel(
    const int* __restrict__ bin_base, const int* __restrict__ temp,
    int* __restrict__ col, int* __restrict__ rowptr, int n_tot, int nbins) {
    __shared__ int srt[BCAP];
    __shared__ int cur[BINW];
    __shared__ int pfx[BINW];
    __shared__ int red[256];
    int b = blockIdx.x;
    int start = b << BSH;
    int nodes = n_tot - start; if (nodes > BINW) nodes = BINW;
    int t = threadIdx.x;
    int base = bin_base[b];
    int count = bin_base[b + 1] - base;
    const int* __restrict__ tb = temp + (size_t)b * BSLOT;
    for (int i = t; i < BINW; i += 256) cur[i] = 0;
    __syncthreads();
    for (int i = t; i < count; i += 256)
        atomicAdd(&cur[(tb[i] >> 16) & (BINW - 1)], 1);
    __syncthreads();
    int a0 = cur[2 * t], a1 = cur[2 * t + 1];
    red[t] = a0 + a1;
    __syncthreads();
    for (int off = 1; off < 256; off <<= 1) {
        int u = (t >= off) ? red[t - off] : 0;
        __syncthreads();
        red[t] += u;
        __syncthreads();
    }
    int excl = red[t] - (a0 + a1);
    pfx[2 * t] = excl;
    pfx[2 * t + 1] = excl + a0;
    __syncthreads();
    for (int i = t; i < nodes; i += 256) rowptr[start + i] = base + pfx[i];
    if (b == nbins - 1 && t == 0) rowptr[n_tot] = base + count;
    for (int i = t; i < BINW; i += 256) cur[i] = pfx[i];
    __syncthreads();
    if (count <= BCAP) {
        for (int i = t; i < count; i += 256) {
            int v = tb[i];
            int p = atomicAdd(&cur[(v >> 16) & (BINW - 1)], 1);
            srt[p] = v & 0xFFFF;
        }
        __syncthreads();
        for (int i = t; i < count; i += 256) col[base + i] = srt[i];
    } else {  // fallback (not expected): direct global scatter
        for (int i = t; i < count; i += 256) {
            int v = tb[i];
            int p = atomicAdd(&cur[(v >> 16) & (BINW - 1)], 1);
            col[base + p] = v & 0xFFFF;
        }
    }
}

// ---------------- W pack: fp32 [k][n] -> MFMA B-fragment order, split bf16 hi/lo ----------------

struct WSrc { const float* a[15]; const float* b[15]; };

__global__ __launch_bounds__(256) void pack_w_kernel(WSrc src, short* __restrict__ whi,
                                                     short* __restrict__ wlo) {
    int idx = blockIdx.x * 256 + threadIdx.x;   // (mat, kc, ct, lane)
    if (idx >= 15 * 4 * 8 * 64) return;
    int lane = idx & 63;
    int ct = (idx >> 6) & 7;
    int kc = (idx >> 9) & 3;
    int mat = idx >> 11;
    const float* A = src.a[mat];
    const float* Bp = src.b[mat];
    int n = ct * 16 + (lane & 15);
    int kbase = kc * 32 + (lane >> 4) * 8;
    size_t o = (size_t)idx * 8;
    for (int j = 0; j < 8; ++j) {
        float v = A[(size_t)(kbase + j) * H + n];
        if (Bp) v += Bp[(size_t)(kbase + j) * H + n];
        short h = f2bf(v);
        whi[o + j] = h;
        wlo[o + j] = f2bf(v - bf2f(h));
    }
}

// ---------------- fp32 -> fp16 mirror convert (layer-0 inputs, both matrices) ----------------

__global__ __launch_bounds__(256) void cvt16_kernel(const float* __restrict__ xa, int n4a,
                                                    const float* __restrict__ xb, int n4b,
                                                    _Float16* __restrict__ ya,
                                                    _Float16* __restrict__ yb) {
    int i = blockIdx.x * 256 + threadIdx.x;
    const float* x; _Float16* y;
    if (i < n4a) { x = xa + (size_t)i * 4; y = ya + (size_t)i * 4; }
    else if (i < n4a + n4b) { x = xb + (size_t)(i - n4a) * 4; y = yb + (size_t)(i - n4a) * 4; }
    else return;
    f32x4 v = *(const f32x4*)x;
    half4v h;
#pragma unroll
    for (int k = 0; k < 4; ++k) h[k] = (_Float16)v[k];
    *(half4v*)y = h;
}

// ---------------- scalar-base fp16 segment mean (R5-proven codegen; DO NOT TOUCH body) -----
// Takes beg/end directly (caller batches the rowptr loads). Full chunks: col[e..e+15]
// contiguous + wave-uniform -> compiler merges to wide s_loads, 16 gathers overlapped
// per chunk. Tails carry the clamps (run once per row).

__device__ __forceinline__ float2 seg16(const _Float16* __restrict__ x,
                                        const int* __restrict__ col,
                                        int beg, int end, int voff) {
    float ax0 = 0.f, ax1 = 0.f, ax2 = 0.f, ax3 = 0.f;
    float ay0 = 0.f, ay1 = 0.f, ay2 = 0.f, ay3 = 0.f;
    int e = beg;
    while (e + 16 <= end) {               // uniform loop control
        half2v v[16];
#pragma unroll
        for (int i = 0; i < 16; ++i) {
            int si = __builtin_amdgcn_readfirstlane(col[e + i]);   // SGPR row index
            v[i] = *(const half2v*)(x + (size_t)si * H + voff);    // saddr + voffset
        }
#pragma unroll
        for (int i = 0; i < 16; i += 4) {
            ax0 += (float)v[i + 0][0]; ay0 += (float)v[i + 0][1];
            ax1 += (float)v[i + 1][0]; ay1 += (float)v[i + 1][1];
            ax2 += (float)v[i + 2][0]; ay2 += (float)v[i + 2][1];
            ax3 += (float)v[i + 3][0]; ay3 += (float)v[i + 3][1];
        }
        e += 16;
    }
    int rem = end - e;
    if (rem > 8) {                        // 9..15 left: one 16-wide masked tail
        int last = end - 1;
        half2v v[16];
#pragma unroll
        for (int i = 0; i < 16; ++i) {
            int p = e + i; if (p > last) p = last;
            int si = __builtin_amdgcn_readfirstlane(col[p]);
            v[i] = *(const half2v*)(x + (size_t)si * H + voff);
        }
#pragma unroll
        for (int i = 0; i < 16; ++i) {
            float m = (i < rem) ? 1.0f : 0.0f;
            float fx = (float)v[i][0], fy = (float)v[i][1];
            if ((i & 3) == 0) { ax0 = fmaf(fx, m, ax0); ay0 = fmaf(fy, m, ay0); }
            else if ((i & 3) == 1) { ax1 = fmaf(fx, m, ax1); ay1 = fmaf(fy, m, ay1); }
            else if ((i & 3) == 2) { ax2 = fmaf(fx, m, ax2); ay2 = fmaf(fy, m, ay2); }
            else { ax3 = fmaf(fx, m, ax3); ay3 = fmaf(fy, m, ay3); }
        }
    } else if (rem > 0) {                 // 1..8 left: one 8-wide masked tail
        int last = end - 1;
        half2v v[8];
#pragma unroll
        for (int i = 0; i < 8; ++i) {
            int p = e + i; if (p > last) p = last;
            int si = __builtin_amdgcn_readfirstlane(col[p]);
            v[i] = *(const half2v*)(x + (size_t)si * H + voff);
        }
#pragma unroll
        for (int i = 0; i < 8; ++i) {
            float m = (i < rem) ? 1.0f : 0.0f;
            float fx = (float)v[i][0], fy = (float)v[i][1];
            if ((i & 3) == 0) { ax0 = fmaf(fx, m, ax0); ay0 = fmaf(fy, m, ay0); }
            else if ((i & 3) == 1) { ax1 = fmaf(fx, m, ax1); ay1 = fmaf(fy, m, ay1); }
            else if ((i & 3) == 2) { ax2 = fmaf(fx, m, ax2); ay2 = fmaf(fy, m, ay2); }
            else { ax3 = fmaf(fx, m, ax3); ay3 = fmaf(fy, m, ay3); }
        }
    }
    float sx = (ax0 + ax1) + (ax2 + ax3);
    float sy = (ay0 + ay1) + (ay2 + ay3);
    int c = end - beg; if (c < 1) c = 1;
    float inv = 1.0f / (float)c;
    return (float2){sx * inv, sy * inv};
}

// ---------------- fused SAGE layer body: 8-wave (512-thread) blocks over 64-row tiles -----
// Gather: wave w owns rows 8w..8w+7. NEW vs R11: the 9 rowptr values for those rows are
// prefetched in ONE batch (contiguous, wave-uniform -> merged s_load_dwordx8) instead of
// 2 scalar loads serially inside each row's chain (~200cy/row saved). seg16 inner loop
// is byte-identical to the proven R5 form. Ragged last block takes the per-row path.

struct GTerm {
    const _Float16* x;   // gather source mirror (kind: gather if non-null)
    int rbase;           // rowptr base index for this edge type
    const short* hi;     // pre-split planes (kind: copy if non-null)
    const short* lo;
    const float* f;      // fp32 source (layer 0 copy)
};

template <int NIN>
__device__ __forceinline__ void layer_body(
    short* __restrict__ Ahi, short* __restrict__ Alo,
    GTerm t0, GTerm t1, GTerm t2,
    const int* __restrict__ rowptr, const int* __restrict__ col,
    const short* __restrict__ whi, const short* __restrict__ wlo,
    int mat0, int mat1, int mat2,
    const float* __restrict__ b0, const float* __restrict__ b1,
    _Float16* __restrict__ out16, short* __restrict__ ohi, short* __restrict__ olo,
    int n_rows, int relu, int bx) {
    const int tid = threadIdx.x;
    const int lane = tid & 63;
    const int wave = __builtin_amdgcn_readfirstlane(tid >> 6);   // 0..7
    const int r0 = bx * 64;
    const int ct0 = wave;              // one 16-col tile per wave
    const int m16 = lane & 15;
    const int acol = (lane >> 4) * 8;

    f32x4 acc[4];
#pragma unroll
    for (int mt = 0; mt < 4; ++mt) acc[mt] = (f32x4){0.f, 0.f, 0.f, 0.f};

    const GTerm terms[3] = {t0, t1, t2};
    const int marr[3] = {mat0, mat1, mat2};

#pragma unroll
    for (int m = 0; m < NIN; ++m) {
        const GTerm& T = terms[m];
        __syncthreads();
        if (T.x) {                          // gather-mean term: wave w owns rows 8w..8w+7
            int voff = lane * 2;
            int r0w = r0 + wave * 8;
            if (r0w + 8 <= n_rows) {        // fast path: batched rowptr prefetch
                int rp[9];
#pragma unroll
                for (int i = 0; i < 9; ++i) rp[i] = rowptr[T.rbase + r0w + i];
                for (int rr = 0; rr < 8; ++rr) {
                    int lrow = wave * 8 + rr;
                    float2 s = seg16(T.x, col, rp[rr], rp[rr + 1], voff);
                    short h0 = f2bf(s.x), h1 = f2bf(s.y);
                    *(short2v*)&Ahi[lrow * RS + voff] = (short2v){h0, h1};
                    *(short2v*)&Alo[lrow * RS + voff] =
                        (short2v){f2bf(s.x - bf2f(h0)), f2bf(s.y - bf2f(h1))};
                }
            } else {                        // ragged last block: per-row clamped
                for (int rr = 0; rr < 8; ++rr) {
                    int lrow = wave * 8 + rr;
                    int gr = r0w + rr;
                    if (gr >= n_rows) gr = n_rows - 1;   // dup row: harmless recompute
                    int rb = T.rbase + gr;
                    float2 s = seg16(T.x, col, rowptr[rb], rowptr[rb + 1], voff);
                    short h0 = f2bf(s.x), h1 = f2bf(s.y);
                    *(short2v*)&Ahi[lrow * RS + voff] = (short2v){h0, h1};
                    *(short2v*)&Alo[lrow * RS + voff] =
                        (short2v){f2bf(s.x - bf2f(h0)), f2bf(s.y - bf2f(h1))};
                }
            }
        } else if (T.hi) {                  // pre-split planes: pure copy
#pragma unroll
            for (int i = 0; i < 4; ++i) {
                int f = tid + i * 512;
                int row = f >> 5;
                int c4 = (f & 31) * 4;
                int gr = r0 + row;
                if (gr >= n_rows) gr = n_rows - 1;
                size_t o = (size_t)gr * H + c4;
                *(short4v*)&Ahi[row * RS + c4] = *(const short4v*)&T.hi[o];
                *(short4v*)&Alo[row * RS + c4] = *(const short4v*)&T.lo[o];
            }
        } else {                            // fp32 (layer 0): split on stage
            const float* __restrict__ A = T.f;
#pragma unroll
            for (int i = 0; i < 4; ++i) {
                int f = tid + i * 512;
                int row = f >> 5;
                int c4 = (f & 31) * 4;
                int gr = r0 + row;
                if (gr >= n_rows) gr = n_rows - 1;
                float4 v = *(const float4*)&A[(size_t)gr * H + c4];
                short h0 = f2bf(v.x), h1 = f2bf(v.y), h2 = f2bf(v.z), h3 = f2bf(v.w);
                *(short4v*)&Ahi[row * RS + c4] = (short4v){h0, h1, h2, h3};
                *(short4v*)&Alo[row * RS + c4] =
                    (short4v){f2bf(v.x - bf2f(h0)), f2bf(v.y - bf2f(h1)),
                              f2bf(v.z - bf2f(h2)), f2bf(v.w - bf2f(h3))};
            }
        }
        __syncthreads();
        const short* __restrict__ wh = whi + (size_t)marr[m] * (H * H);
        const short* __restrict__ wl = wlo + (size_t)marr[m] * (H * H);
        short8 bh[2], bl[2];
        {
            size_t f0 = ((size_t)ct0 * 64 + lane) * 8;
            bh[0] = *(const short8*)&wh[f0];
            bl[0] = *(const short8*)&wl[f0];
        }
#pragma unroll
        for (int kc = 0; kc < 4; ++kc) {
            if (kc < 3) {
                int nb = (kc + 1) & 1;
                size_t f = ((size_t)((kc + 1) * 8 + ct0) * 64 + lane) * 8;
                bh[nb] = *(const short8*)&wh[f];
                bl[nb] = *(const short8*)&wl[f];
            }
            int cb = kc & 1;
#pragma unroll
            for (int mt = 0; mt < 4; ++mt) {
                short8 ah = *(const short8*)&Ahi[(mt * 16 + m16) * RS + kc * 32 + acol];
                short8 al = *(const short8*)&Alo[(mt * 16 + m16) * RS + kc * 32 + acol];
                acc[mt] = __builtin_amdgcn_mfma_f32_16x16x32_bf16(ah, bh[cb], acc[mt], 0, 0, 0);
                acc[mt] = __builtin_amdgcn_mfma_f32_16x16x32_bf16(al, bh[cb], acc[mt], 0, 0, 0);
                acc[mt] = __builtin_amdgcn_mfma_f32_16x16x32_bf16(ah, bl[cb], acc[mt], 0, 0, 0);
            }
        }
    }

    const int rquad = (lane >> 4) * 4;
    const int ncol = lane & 15;
    {
        int n = ct0 * 16 + ncol;
        float bs = b0[n];
        if (b1) bs += b1[n];
#pragma unroll
        for (int mt = 0; mt < 4; ++mt) {
#pragma unroll
            for (int reg = 0; reg < 4; ++reg) {
                int gr = r0 + mt * 16 + rquad + reg;
                if (gr < n_rows) {
                    float v = acc[mt][reg] + bs;
                    if (relu) v = v > 0.f ? v : 0.01f * v;
                    size_t o = (size_t)gr * H + n;
                    out16[o] = (_Float16)v;
                    short h = f2bf(v);
                    ohi[o] = h;
                    olo[o] = f2bf(v - bf2f(h));
                }
            }
        }
    }
}

// One launch per layer: blocks [0, nbp) run the pheno path (3 terms), blocks [nbp, ...)
// run the gene path (2 terms). 512 threads (8 waves) per block.
struct LayerArgs {
    GTerm p0, p1, p2, g0, g1;
    const int* rowptr; const int* col;
    const short* whi; const short* wlo;
    int pm0, pm1, pm2, gm0, gm1;
    const float* pb0; const float* pb1; const float* gb0;
    _Float16* pout16; short* poh; short* pol; int np;
    _Float16* gout16; short* goh; short* gol; int ng;
    int relu; int nbp;
};

__global__ __launch_bounds__(512, 4) void fused_layer(LayerArgs a) {
    __shared__ short Ahi[64 * RS];
    __shared__ short Alo[64 * RS];
    int bx = blockIdx.x;
    if (bx < a.nbp) {
        layer_body<3>(Ahi, Alo, a.p0, a.p1, a.p2, a.rowptr, a.col, a.whi, a.wlo,
                      a.pm0, a.pm1, a.pm2, a.pb0, a.pb1,
                      a.pout16, a.poh, a.pol, a.np, a.relu, bx);
    } else {
        layer_body<2>(Ahi, Alo, a.g0, a.g1, a.g1, a.rowptr, a.col, a.whi, a.wlo,
                      a.gm0, a.gm1, 0, a.gb0, nullptr,
                      a.gout16, a.goh, a.gol, a.ng, a.relu, bx - a.nbp);
    }
}

// ---------------- edge decoder: sigmoid(dot(xp[i], xg[j])) on fp16 mirrors ----------------

__global__ __launch_bounds__(256) void scores_kernel(const _Float16* __restrict__ xp,
                                                     const _Float16* __restrict__ xg,
                                                     const int* __restrict__ eli, int E,
                                                     float* __restrict__ out) {
    int lane16 = threadIdx.x & 15;
    int sub = threadIdx.x >> 4;     // 16 edges per block
    int e = blockIdx.x * 16 + sub;
    if (e >= E) return;
    int ip = eli[e];
    int ig = eli[E + e];
    half8v a = *(const half8v*)&xp[(size_t)ip * H + lane16 * 8];
    half8v b = *(const half8v*)&xg[(size_t)ig * H + lane16 * 8];
    float s = 0.f;
#pragma unroll
    for (int k = 0; k < 8; ++k) s += (float)a[k] * (float)b[k];
#pragma unroll
    for (int off = 8; off; off >>= 1) s += __shfl_xor(s, off, 16);
    if (lane16 == 0) out[e] = 1.0f / (1.0f + expf(-s));
}

// ---------------- host ----------------

extern "C" void kernel_launch(void* const* d_in, const int* in_sizes, int n_in,
                              void* d_out, int out_size, void* d_ws, size_t ws_size,
                              hipStream_t stream) {
    const float* x_pheno = (const float*)d_in[0];
    const float* x_gene  = (const float*)d_in[1];
    const float* Wl_isa  = (const float*)d_in[2];
    const float* bl_isa  = (const float*)d_in[3];
    const float* Wr_isa  = (const float*)d_in[4];
    const float* Wl_rel  = (const float*)d_in[5];
    const float* bl_rel  = (const float*)d_in[6];
    const float* Wr_rel  = (const float*)d_in[7];
    const float* Wl_rev  = (const float*)d_in[8];
    const float* bl_rev  = (const float*)d_in[9];
    const float* Wr_rev  = (const float*)d_in[10];
    const int* e_isa = (const int*)d_in[11];
    const int* e_rel = (const int*)d_in[12];
    const int* e_rev = (const int*)d_in[13];
    const int* e_lbl = (const int*)d_in[14];
    const int E_isa = in_sizes[11] / 2;
    const int E_rel = in_sizes[12] / 2;
    const int E_rev = in_sizes[13] / 2;
    const int E_lbl = in_sizes[14] / 2;
    const int NP = in_sizes[0] / H;
    const int NG = in_sizes[1] / H;
    const int n_tot = NP + NG + NP;
    const int E_tot = E_isa + E_rel + E_rev;
    const int nbins = (n_tot + BINW - 1) / BINW;

    char* ws = (char*)d_ws;
    auto alloc = [&](size_t bytes) -> char* {
        char* p = ws;
        ws += (bytes + 255) & ~(size_t)255;
        return p;
    };
    int* rowptr  = (int*)alloc((size_t)(n_tot + 1) * 4);
    int* col     = (int*)alloc((size_t)E_tot * 4 + 64);   // +64B slack
    int* temp    = (int*)alloc((size_t)nbins * BSLOT * 4);
    int* bin_cur = (int*)alloc((size_t)nbins * 16 * 4);   // 64B-strided counters
    int* bin_base= (int*)alloc((size_t)(nbins + 1) * 4);
    short* whi = (short*)alloc((size_t)15 * H * H * sizeof(short));
    short* wlo = (short*)alloc((size_t)15 * H * H * sizeof(short));
    _Float16* xpm[2], *xgm[2];
    xpm[0] = (_Float16*)alloc((size_t)NP * H * sizeof(_Float16));
    xpm[1] = (_Float16*)alloc((size_t)NP * H * sizeof(_Float16));
    xgm[0] = (_Float16*)alloc((size_t)NG * H * sizeof(_Float16));
    xgm[1] = (_Float16*)alloc((size_t)NG * H * sizeof(_Float16));
    short* xph = (short*)alloc((size_t)NP * H * sizeof(short));
    short* xpl = (short*)alloc((size_t)NP * H * sizeof(short));
    short* xgh = (short*)alloc((size_t)NG * H * sizeof(short));
    short* xgl = (short*)alloc((size_t)NG * H * sizeof(short));

    // ---- CSR build (every call; ws is re-poisoned by the harness) ----
    hipMemsetAsync(bin_cur, 0, (size_t)nbins * 16 * 4, stream);
    bin_scatter_kernel<<<(E_tot + KEDGE - 1) / KEDGE, 256, 0, stream>>>(
        e_isa, E_isa, e_rel, E_rel, e_rev, E_rev, bin_cur, temp, NP, NG, nbins, E_tot);
    scan_bins<<<1, 1024, 0, stream>>>(bin_cur, nbins, bin_base);
    bin_sort_kernel<<<nbins, 256, 0, stream>>>(bin_base, temp, col, rowptr, n_tot, nbins);

    // ---- W pack: per layer slots {Wl_isa, Wl_rev, Wsum=Wr_isa+Wr_rev, Wl_rel, Wr_rel} ----
    WSrc src;
    for (int l = 0; l < 3; ++l) {
        src.a[l * 5 + 0] = Wl_isa + (size_t)l * H * H;  src.b[l * 5 + 0] = nullptr;
        src.a[l * 5 + 1] = Wl_rev + (size_t)l * H * H;  src.b[l * 5 + 1] = nullptr;
        src.a[l * 5 + 2] = Wr_isa + (size_t)l * H * H;  src.b[l * 5 + 2] = Wr_rev + (size_t)l * H * H;
        src.a[l * 5 + 3] = Wl_rel + (size_t)l * H * H;  src.b[l * 5 + 3] = nullptr;
        src.a[l * 5 + 4] = Wr_rel + (size_t)l * H * H;  src.b[l * 5 + 4] = nullptr;
    }
    pack_w_kernel<<<(15 * 4 * 8 * 64 + 255) / 256, 256, 0, stream>>>(src, whi, wlo);

    // ---- layer-0 fp16 mirrors of the inputs (set 0) ----
    cvt16_kernel<<<((NP + NG) * 32 + 255) / 256, 256, 0, stream>>>(
        x_pheno, NP * 32, x_gene, NG * 32, xpm[0], xgm[0]);

    // ---- 3 fused layers (one launch each; p blocks lead, g blocks backfill) ----
    const short *pph = nullptr, *ppl = nullptr, *pgh = nullptr, *pgl = nullptr;
    const int nbp = (NP + 63) / 64, nbg = (NG + 63) / 64;
    for (int l = 0; l < 3; ++l) {
        int rs = l & 1;
        int wsid = rs ^ 1;
        LayerArgs a;
        a.p0 = GTerm{xpm[rs], 0, nullptr, nullptr, nullptr};
        a.p1 = GTerm{xgm[rs], NP + NG, nullptr, nullptr, nullptr};
        a.p2 = GTerm{nullptr, 0, pph, ppl, l == 0 ? x_pheno : nullptr};
        a.g0 = GTerm{xpm[rs], NP, nullptr, nullptr, nullptr};
        a.g1 = GTerm{nullptr, 0, pgh, pgl, l == 0 ? x_gene : nullptr};
        a.rowptr = rowptr; a.col = col; a.whi = whi; a.wlo = wlo;
        a.pm0 = l * 5 + 0; a.pm1 = l * 5 + 1; a.pm2 = l * 5 + 2;
        a.gm0 = l * 5 + 3; a.gm1 = l * 5 + 4;
        a.pb0 = bl_isa + (size_t)l * H; a.pb1 = bl_rev + (size_t)l * H;
        a.gb0 = bl_rel + (size_t)l * H;
        a.pout16 = xpm[wsid]; a.poh = xph; a.pol = xpl; a.np = NP;
        a.gout16 = xgm[wsid]; a.goh = xgh; a.gol = xgl; a.ng = NG;
        a.relu = (l < 2) ? 1 : 0; a.nbp = nbp;
        fused_layer<<<nbp + nbg, 512, 0, stream>>>(a);
        pph = xph; ppl = xpl; pgh = xgh; pgl = xgl;
    }

    // ---- decoder (layer 2 wrote mirror set 1) ----
    scores_kernel<<<(E_lbl + 15) / 16, 256, 0, stream>>>(xpm[1], xgm[1], e_lbl, E_lbl,
                                                         (float*)d_out);
}

// Round 14
// 574.842 us; speedup vs baseline: 1.3901x; 1.0283x over previous
//
#include <hip/hip_runtime.h>
#include <hip/hip_bf16.h>
#include <math.h>

#define H 128
#define RS 136    // LDS row stride in shorts (128 + 8 pad; keeps ds_read_b128 16B-aligned)
#define BSH 9     // bin shift: 512 nodes per bin
#define BINW 512
#define BCAP 11264  // max edges/bin for LDS sort
#define BSLOT 12288 // per-bin slot capacity in temp (direct scatter)
#define KEDGE 4096  // edges per partition block
#define EPT 16      // edges per thread (KEDGE/256)
#define MAXBINS 1024
#define NB_PACK ((15 * 4 * 8 * 64 + 255) / 256)   // 120 blocks for W pack

typedef __attribute__((ext_vector_type(8))) short short8;
typedef __attribute__((ext_vector_type(4))) short short4v;
typedef __attribute__((ext_vector_type(2))) short short2v;
typedef __attribute__((ext_vector_type(4))) float f32x4;
typedef __attribute__((ext_vector_type(2))) _Float16 half2v;
typedef __attribute__((ext_vector_type(4))) _Float16 half4v;
typedef __attribute__((ext_vector_type(8))) _Float16 half8v;

// fp32 -> bf16 (RNE); values here are finite (no NaN handling needed)
__device__ __forceinline__ short f2bf(float f) {
    unsigned u = __float_as_uint(f);
    u += 0x7fff + ((u >> 16) & 1);
    return (short)(u >> 16);
}
__device__ __forceinline__ float bf2f(short h) {
    return __uint_as_float(((unsigned)(unsigned short)h) << 16);
}

// ---------------- CSR build (direct slot scatter -> scan -> in-bin sort+rowptr) ----------
// Node space concatenated: [NP(isa) | NG(rel) | NP(rev)].

// scatter body (verbatim logic; bx = scatter-block index)
__device__ __forceinline__ void scatter_body(
    int* hist, int* cur, int bx,
    const int* __restrict__ e0, int E0, const int* __restrict__ e1, int E1,
    const int* __restrict__ e2, int E2, int* __restrict__ bin_cur,
    int* __restrict__ temp, int NPn, int NGn, int nbins, int E_tot) {
    int t = threadIdx.x;
    for (int i = t; i < nbins; i += 256) hist[i] = 0;
    __syncthreads();
    int vals[EPT], bins[EPT];
    int base_e = bx * KEDGE;
#pragma unroll
    for (int j = 0; j < EPT; ++j) {
        int g = base_e + j * 256 + t;      // coalesced within each j-step
        int b = -1, v = 0;
        if (g < E_tot) {
            const int* ed; int E, lo, nbase;
            if (g < E0) { ed = e0; E = E0; lo = g; nbase = 0; }
            else if (g < E0 + E1) { ed = e1; E = E1; lo = g - E0; nbase = NPn; }
            else { ed = e2; E = E2; lo = g - E0 - E1; nbase = NPn + NGn; }
            int src = ed[lo];
            int gdst = nbase + ed[E + lo];
            v = src | ((gdst & (BINW - 1)) << 16);
            b = gdst >> BSH;
            atomicAdd(&hist[b], 1);        // LDS atomic
        }
        vals[j] = v;
        bins[j] = b;
    }
    __syncthreads();
    for (int i = t; i < nbins; i += 256) {
        int h = hist[i];
        cur[i] = h ? atomicAdd(&bin_cur[i * 16], h) : 0;   // reserve run (local slot base)
    }
    __syncthreads();
#pragma unroll
    for (int j = 0; j < EPT; ++j) {
        if (bins[j] >= 0) {
            int p = atomicAdd(&cur[bins[j]], 1);           // LDS atomic -> local slot
            if (p < BSLOT) temp[(size_t)bins[j] * BSLOT + p] = vals[j];
        }
    }
}

// W pack body: fp32 [k][n] -> MFMA B-fragment order, split bf16 hi/lo.
// B-operand layout: n = ct*16 + (lane&15), k = kc*32 + (lane>>4)*8 + j.
struct WSrc { const float* a[15]; const float* b[15]; };

__device__ __forceinline__ void pack_body(int bx, const WSrc& src,
                                          short* __restrict__ whi, short* __restrict__ wlo) {
    int idx = bx * 256 + threadIdx.x;   // (mat, kc, ct, lane)
    if (idx >= 15 * 4 * 8 * 64) return;
    int lane = idx & 63;
    int ct = (idx >> 6) & 7;
    int kc = (idx >> 9) & 3;
    int mat = idx >> 11;
    const float* A = src.a[mat];
    const float* Bp = src.b[mat];
    int n = ct * 16 + (lane & 15);
    int kbase = kc * 32 + (lane >> 4) * 8;
    size_t o = (size_t)idx * 8;
    for (int j = 0; j < 8; ++j) {
        float v = A[(size_t)(kbase + j) * H + n];
        if (Bp) v += Bp[(size_t)(kbase + j) * H + n];
        short h = f2bf(v);
        whi[o + j] = h;
        wlo[o + j] = f2bf(v - bf2f(h));
    }
}

// cvt16 body: fp32 -> fp16 mirror (layer-0 inputs, both matrices)
__device__ __forceinline__ void cvt_body(int bx, const float* __restrict__ xa, int n4a,
                                         const float* __restrict__ xb, int n4b,
                                         _Float16* __restrict__ ya, _Float16* __restrict__ yb) {
    int i = bx * 256 + threadIdx.x;
    const float* x; _Float16* y;
    if (i < n4a) { x = xa + (size_t)i * 4; y = ya + (size_t)i * 4; }
    else if (i < n4a + n4b) { x = xb + (size_t)(i - n4a) * 4; y = yb + (size_t)(i - n4a) * 4; }
    else return;
    f32x4 v = *(const f32x4*)x;
    half4v h;
#pragma unroll
    for (int k = 0; k < 4; ++k) h[k] = (_Float16)v[k];
    *(half4v*)y = h;
}

// Combined launch: blocks [0,nbs) scatter | [nbs,nbs+NB_PACK) pack | rest cvt.
// The three are data-independent; merging hides pack+cvt under scatter and saves
// two launch gaps.
struct ComboArgs {
    const int* e0; int E0; const int* e1; int E1; const int* e2; int E2;
    int* bin_cur; int* temp; int NPn; int NGn; int nbins; int E_tot; int nbs;
    WSrc src; short* whi; short* wlo;
    const float* xa; int n4a; const float* xb; int n4b;
    _Float16* ya; _Float16* yb;
};

__global__ __launch_bounds__(256) void combo_kernel(ComboArgs a) {
    __shared__ int hist[MAXBINS];
    __shared__ int cur[MAXBINS];
    int bx = blockIdx.x;
    if (bx < a.nbs) {
        scatter_body(hist, cur, bx, a.e0, a.E0, a.e1, a.E1, a.e2, a.E2,
                     a.bin_cur, a.temp, a.NPn, a.NGn, a.nbins, a.E_tot);
    } else if (bx < a.nbs + NB_PACK) {
        pack_body(bx - a.nbs, a.src, a.whi, a.wlo);
    } else {
        cvt_body(bx - a.nbs - NB_PACK, a.xa, a.n4a, a.xb, a.n4b, a.ya, a.yb);
    }
}

__global__ __launch_bounds__(1024) void scan_bins(const int* __restrict__ bin_cur, int nbins,
                                                  int* __restrict__ bin_base) {
    __shared__ int sh[1024];
    int t = threadIdx.x;
    int v = 0;
    if (t < nbins) { v = bin_cur[t * 16]; if (v > BSLOT) v = BSLOT; }
    sh[t] = v;
    __syncthreads();
    for (int off = 1; off < 1024; off <<= 1) {
        int u = (t >= off) ? sh[t - off] : 0;
        __syncthreads();
        sh[t] += u;
        __syncthreads();
    }
    if (t < nbins) bin_base[t] = sh[t] - v;    // exclusive
    if (t == nbins - 1) bin_base[nbins] = sh[t];
}

__global__ __launch_bounds__(256) void bin_sort_kernel(
    const int* __restrict__ bin_base, const int* __restrict__ temp,
    int* __restrict__ col, int* __restrict__ rowptr, int n_tot, int nbins) {
    __shared__ int srt[BCAP];
    __shared__ int cur[BINW];
    __shared__ int pfx[BINW];
    __shared__ int red[256];
    int b = blockIdx.x;
    int start = b << BSH;
    int nodes = n_tot - start; if (nodes > BINW) nodes = BINW;
    int t = threadIdx.x;
    int base = bin_base[b];
    int count = bin_base[b + 1] - base;
    const int* __restrict__ tb = temp + (size_t)b * BSLOT;
    for (int i = t; i < BINW; i += 256) cur[i] = 0;
    __syncthreads();
    for (int i = t; i < count; i += 256)
        atomicAdd(&cur[(tb[i] >> 16) & (BINW - 1)], 1);
    __syncthreads();
    int a0 = cur[2 * t], a1 = cur[2 * t + 1];
    red[t] = a0 + a1;
    __syncthreads();
    for (int off = 1; off < 256; off <<= 1) {
        int u = (t >= off) ? red[t - off] : 0;
        __syncthreads();
        red[t] += u;
        __syncthreads();
    }
    int excl = red[t] - (a0 + a1);
    pfx[2 * t] = excl;
    pfx[2 * t + 1] = excl + a0;
    __syncthreads();
    for (int i = t; i < nodes; i += 256) rowptr[start + i] = base + pfx[i];
    if (b == nbins - 1 && t == 0) rowptr[n_tot] = base + count;
    for (int i = t; i < BINW; i += 256) cur[i] = pfx[i];
    __syncthreads();
    if (count <= BCAP) {
        for (int i = t; i < count; i += 256) {
            int v = tb[i];
            int p = atomicAdd(&cur[(v >> 16) & (BINW - 1)], 1);
            srt[p] = v & 0xFFFF;
        }
        __syncthreads();
        for (int i = t; i < count; i += 256) col[base + i] = srt[i];
    } else {  // fallback (not expected): direct global scatter
        for (int i = t; i < count; i += 256) {
            int v = tb[i];
            int p = atomicAdd(&cur[(v >> 16) & (BINW - 1)], 1);
            col[base + p] = v & 0xFFFF;
        }
    }
}

// ---------------- scalar-base fp16 segment mean (R5-proven codegen; DO NOT TOUCH body) -----
// Takes beg/end directly (caller batches the rowptr loads). Full chunks: col[e..e+15]
// contiguous + wave-uniform -> compiler merges to wide s_loads, 16 gathers overlapped
// per chunk. Tails carry the clamps (run once per row).

__device__ __forceinline__ float2 seg16(const _Float16* __restrict__ x,
                                        const int* __restrict__ col,
                                        int beg, int end, int voff) {
    float ax0 = 0.f, ax1 = 0.f, ax2 = 0.f, ax3 = 0.f;
    float ay0 = 0.f, ay1 = 0.f, ay2 = 0.f, ay3 = 0.f;
    int e = beg;
    while (e + 16 <= end) {               // uniform loop control
        half2v v[16];
#pragma unroll
        for (int i = 0; i < 16; ++i) {
            int si = __builtin_amdgcn_readfirstlane(col[e + i]);   // SGPR row index
            v[i] = *(const half2v*)(x + (size_t)si * H + voff);    // saddr + voffset
        }
#pragma unroll
        for (int i = 0; i < 16; i += 4) {
            ax0 += (float)v[i + 0][0]; ay0 += (float)v[i + 0][1];
            ax1 += (float)v[i + 1][0]; ay1 += (float)v[i + 1][1];
            ax2 += (float)v[i + 2][0]; ay2 += (float)v[i + 2][1];
            ax3 += (float)v[i + 3][0]; ay3 += (float)v[i + 3][1];
        }
        e += 16;
    }
    int rem = end - e;
    if (rem > 8) {                        // 9..15 left: one 16-wide masked tail
        int last = end - 1;
        half2v v[16];
#pragma unroll
        for (int i = 0; i < 16; ++i) {
            int p = e + i; if (p > last) p = last;
            int si = __builtin_amdgcn_readfirstlane(col[p]);
            v[i] = *(const half2v*)(x + (size_t)si * H + voff);
        }
#pragma unroll
        for (int i = 0; i < 16; ++i) {
            float m = (i < rem) ? 1.0f : 0.0f;
            float fx = (float)v[i][0], fy = (float)v[i][1];
            if ((i & 3) == 0) { ax0 = fmaf(fx, m, ax0); ay0 = fmaf(fy, m, ay0); }
            else if ((i & 3) == 1) { ax1 = fmaf(fx, m, ax1); ay1 = fmaf(fy, m, ay1); }
            else if ((i & 3) == 2) { ax2 = fmaf(fx, m, ax2); ay2 = fmaf(fy, m, ay2); }
            else { ax3 = fmaf(fx, m, ax3); ay3 = fmaf(fy, m, ay3); }
        }
    } else if (rem > 0) {                 // 1..8 left: one 8-wide masked tail
        int last = end - 1;
        half2v v[8];
#pragma unroll
        for (int i = 0; i < 8; ++i) {
            int p = e + i; if (p > last) p = last;
            int si = __builtin_amdgcn_readfirstlane(col[p]);
            v[i] = *(const half2v*)(x + (size_t)si * H + voff);
        }
#pragma unroll
        for (int i = 0; i < 8; ++i) {
            float m = (i < rem) ? 1.0f : 0.0f;
            float fx = (float)v[i][0], fy = (float)v[i][1];
            if ((i & 3) == 0) { ax0 = fmaf(fx, m, ax0); ay0 = fmaf(fy, m, ay0); }
            else if ((i & 3) == 1) { ax1 = fmaf(fx, m, ax1); ay1 = fmaf(fy, m, ay1); }
            else if ((i & 3) == 2) { ax2 = fmaf(fx, m, ax2); ay2 = fmaf(fy, m, ay2); }
            else { ax3 = fmaf(fx, m, ax3); ay3 = fmaf(fy, m, ay3); }
        }
    }
    float sx = (ax0 + ax1) + (ax2 + ax3);
    float sy = (ay0 + ay1) + (ay2 + ay3);
    int c = end - beg; if (c < 1) c = 1;
    float inv = 1.0f / (float)c;
    return (float2){sx * inv, sy * inv};
}

// ---------------- fused SAGE layer body: 8-wave (512-thread) blocks over 64-row tiles -----
// Gather: wave w owns rows 8w..8w+7; the 9 rowptr values are prefetched in ONE batch
// (contiguous, wave-uniform -> merged s_load). seg16 inner loop is byte-identical to
// the proven R5 form. Ragged last block takes the per-row path.

struct GTerm {
    const _Float16* x;   // gather source mirror (kind: gather if non-null)
    int rbase;           // rowptr base index for this edge type
    const short* hi;     // pre-split planes (kind: copy if non-null)
    const short* lo;
    const float* f;      // fp32 source (layer 0 copy)
};

template <int NIN>
__device__ __forceinline__ void layer_body(
    short* __restrict__ Ahi, short* __restrict__ Alo,
    GTerm t0, GTerm t1, GTerm t2,
    const int* __restrict__ rowptr, const int* __restrict__ col,
    const short* __restrict__ whi, const short* __restrict__ wlo,
    int mat0, int mat1, int mat2,
    const float* __restrict__ b0, const float* __restrict__ b1,
    _Float16* __restrict__ out16, short* __restrict__ ohi, short* __restrict__ olo,
    int n_rows, int relu, int bx) {
    const int tid = threadIdx.x;
    const int lane = tid & 63;
    const int wave = __builtin_amdgcn_readfirstlane(tid >> 6);   // 0..7
    const int r0 = bx * 64;
    const int ct0 = wave;              // one 16-col tile per wave
    const int m16 = lane & 15;
    const int acol = (lane >> 4) * 8;

    f32x4 acc[4];
#pragma unroll
    for (int mt = 0; mt < 4; ++mt) acc[mt] = (f32x4){0.f, 0.f, 0.f, 0.f};

    const GTerm terms[3] = {t0, t1, t2};
    const int marr[3] = {mat0, mat1, mat2};

#pragma unroll
    for (int m = 0; m < NIN; ++m) {
        const GTerm& T = terms[m];
        __syncthreads();
        if (T.x) {                          // gather-mean term: wave w owns rows 8w..8w+7
            int voff = lane * 2;
            int r0w = r0 + wave * 8;
            if (r0w + 8 <= n_rows) {        // fast path: batched rowptr prefetch
                int rp[9];
#pragma unroll
                for (int i = 0; i < 9; ++i) rp[i] = rowptr[T.rbase + r0w + i];
                for (int rr = 0; rr < 8; ++rr) {
                    int lrow = wave * 8 + rr;
                    float2 s = seg16(T.x, col, rp[rr], rp[rr + 1], voff);
                    short h0 = f2bf(s.x), h1 = f2bf(s.y);
                    *(short2v*)&Ahi[lrow * RS + voff] = (short2v){h0, h1};
                    *(short2v*)&Alo[lrow * RS + voff] =
                        (short2v){f2bf(s.x - bf2f(h0)), f2bf(s.y - bf2f(h1))};
                }
            } else {                        // ragged last block: per-row clamped
                for (int rr = 0; rr < 8; ++rr) {
                    int lrow = wave * 8 + rr;
                    int gr = r0w + rr;
                    if (gr >= n_rows) gr = n_rows - 1;   // dup row: harmless recompute
                    int rb = T.rbase + gr;
                    float2 s = seg16(T.x, col, rowptr[rb], rowptr[rb + 1], voff);
                    short h0 = f2bf(s.x), h1 = f2bf(s.y);
                    *(short2v*)&Ahi[lrow * RS + voff] = (short2v){h0, h1};
                    *(short2v*)&Alo[lrow * RS + voff] =
                        (short2v){f2bf(s.x - bf2f(h0)), f2bf(s.y - bf2f(h1))};
                }
            }
        } else if (T.hi) {                  // pre-split planes: pure copy
#pragma unroll
            for (int i = 0; i < 4; ++i) {
                int f = tid + i * 512;
                int row = f >> 5;
                int c4 = (f & 31) * 4;
                int gr = r0 + row;
                if (gr >= n_rows) gr = n_rows - 1;
                size_t o = (size_t)gr * H + c4;
                *(short4v*)&Ahi[row * RS + c4] = *(const short4v*)&T.hi[o];
                *(short4v*)&Alo[row * RS + c4] = *(const short4v*)&T.lo[o];
            }
        } else {                            // fp32 (layer 0): split on stage
            const float* __restrict__ A = T.f;
#pragma unroll
            for (int i = 0; i < 4; ++i) {
                int f = tid + i * 512;
                int row = f >> 5;
                int c4 = (f & 31) * 4;
                int gr = r0 + row;
                if (gr >= n_rows) gr = n_rows - 1;
                float4 v = *(const float4*)&A[(size_t)gr * H + c4];
                short h0 = f2bf(v.x), h1 = f2bf(v.y), h2 = f2bf(v.z), h3 = f2bf(v.w);
                *(short4v*)&Ahi[row * RS + c4] = (short4v){h0, h1, h2, h3};
                *(short4v*)&Alo[row * RS + c4] =
                    (short4v){f2bf(v.x - bf2f(h0)), f2bf(v.y - bf2f(h1)),
                              f2bf(v.z - bf2f(h2)), f2bf(v.w - bf2f(h3))};
            }
        }
        __syncthreads();
        const short* __restrict__ wh = whi + (size_t)marr[m] * (H * H);
        const short* __restrict__ wl = wlo + (size_t)marr[m] * (H * H);
        short8 bh[2], bl[2];
        {
            size_t f0 = ((size_t)ct0 * 64 + lane) * 8;
            bh[0] = *(const short8*)&wh[f0];
            bl[0] = *(const short8*)&wl[f0];
        }
#pragma unroll
        for (int kc = 0; kc < 4; ++kc) {
            if (kc < 3) {
                int nb = (kc + 1) & 1;
                size_t f = ((size_t)((kc + 1) * 8 + ct0) * 64 + lane) * 8;
                bh[nb] = *(const short8*)&wh[f];
                bl[nb] = *(const short8*)&wl[f];
            }
            int cb = kc & 1;
#pragma unroll
            for (int mt = 0; mt < 4; ++mt) {
                short8 ah = *(const short8*)&Ahi[(mt * 16 + m16) * RS + kc * 32 + acol];
                short8 al = *(const short8*)&Alo[(mt * 16 + m16) * RS + kc * 32 + acol];
                acc[mt] = __builtin_amdgcn_mfma_f32_16x16x32_bf16(ah, bh[cb], acc[mt], 0, 0, 0);
                acc[mt] = __builtin_amdgcn_mfma_f32_16x16x32_bf16(al, bh[cb], acc[mt], 0, 0, 0);
                acc[mt] = __builtin_amdgcn_mfma_f32_16x16x32_bf16(ah, bl[cb], acc[mt], 0, 0, 0);
            }
        }
    }

    const int rquad = (lane >> 4) * 4;
    const int ncol = lane & 15;
    {
        int n = ct0 * 16 + ncol;
        float bs = b0[n];
        if (b1) bs += b1[n];
#pragma unroll
        for (int mt = 0; mt < 4; ++mt) {
#pragma unroll
            for (int reg = 0; reg < 4; ++reg) {
                int gr = r0 + mt * 16 + rquad + reg;
                if (gr < n_rows) {
                    float v = acc[mt][reg] + bs;
                    if (relu) v = v > 0.f ? v : 0.01f * v;
                    size_t o = (size_t)gr * H + n;
                    out16[o] = (_Float16)v;
                    short h = f2bf(v);
                    ohi[o] = h;
                    olo[o] = f2bf(v - bf2f(h));
                }
            }
        }
    }
}

// One launch per layer: blocks [0, nbp) run the pheno path (3 terms), blocks [nbp, ...)
// run the gene path (2 terms). 512 threads (8 waves) per block.
struct LayerArgs {
    GTerm p0, p1, p2, g0, g1;
    const int* rowptr; const int* col;
    const short* whi; const short* wlo;
    int pm0, pm1, pm2, gm0, gm1;
    const float* pb0; const float* pb1; const float* gb0;
    _Float16* pout16; short* poh; short* pol; int np;
    _Float16* gout16; short* goh; short* gol; int ng;
    int relu; int nbp;
};

__global__ __launch_bounds__(512, 4) void fused_layer(LayerArgs a) {
    __shared__ short Ahi[64 * RS];
    __shared__ short Alo[64 * RS];
    int bx = blockIdx.x;
    if (bx < a.nbp) {
        layer_body<3>(Ahi, Alo, a.p0, a.p1, a.p2, a.rowptr, a.col, a.whi, a.wlo,
                      a.pm0, a.pm1, a.pm2, a.pb0, a.pb1,
                      a.pout16, a.poh, a.pol, a.np, a.relu, bx);
    } else {
        layer_body<2>(Ahi, Alo, a.g0, a.g1, a.g1, a.rowptr, a.col, a.whi, a.wlo,
                      a.gm0, a.gm1, 0, a.gb0, nullptr,
                      a.gout16, a.goh, a.gol, a.ng, a.relu, bx - a.nbp);
    }
}

// ---------------- edge decoder: sigmoid(dot(xp[i], xg[j])) on fp16 mirrors ----------------

__global__ __launch_bounds__(256) void scores_kernel(const _Float16* __restrict__ xp,
                                                     const _Float16* __restrict__ xg,
                                                     const int* __restrict__ eli, int E,
                                                     float* __restrict__ out) {
    int lane16 = threadIdx.x & 15;
    int sub = threadIdx.x >> 4;     // 16 edges per block
    int e = blockIdx.x * 16 + sub;
    if (e >= E) return;
    int ip = eli[e];
    int ig = eli[E + e];
    half8v a = *(const half8v*)&xp[(size_t)ip * H + lane16 * 8];
    half8v b = *(const half8v*)&xg[(size_t)ig * H + lane16 * 8];
    float s = 0.f;
#pragma unroll
    for (int k = 0; k < 8; ++k) s += (float)a[k] * (float)b[k];
#pragma unroll
    for (int off = 8; off; off >>= 1) s += __shfl_xor(s, off, 16);
    if (lane16 == 0) out[e] = 1.0f / (1.0f + expf(-s));
}

// ---------------- host ----------------

extern "C" void kernel_launch(void* const* d_in, const int* in_sizes, int n_in,
                              void* d_out, int out_size, void* d_ws, size_t ws_size,
                              hipStream_t stream) {
    const float* x_pheno = (const float*)d_in[0];
    const float* x_gene  = (const float*)d_in[1];
    const float* Wl_isa  = (const float*)d_in[2];
    const float* bl_isa  = (const float*)d_in[3];
    const float* Wr_isa  = (const float*)d_in[4];
    const float* Wl_rel  = (const float*)d_in[5];
    const float* bl_rel  = (const float*)d_in[6];
    const float* Wr_rel  = (const float*)d_in[7];
    const float* Wl_rev  = (const float*)d_in[8];
    const float* bl_rev  = (const float*)d_in[9];
    const float* Wr_rev  = (const float*)d_in[10];
    const int* e_isa = (const int*)d_in[11];
    const int* e_rel = (const int*)d_in[12];
    const int* e_rev = (const int*)d_in[13];
    const int* e_lbl = (const int*)d_in[14];
    const int E_isa = in_sizes[11] / 2;
    const int E_rel = in_sizes[12] / 2;
    const int E_rev = in_sizes[13] / 2;
    const int E_lbl = in_sizes[14] / 2;
    const int NP = in_sizes[0] / H;
    const int NG = in_sizes[1] / H;
    const int n_tot = NP + NG + NP;
    const int E_tot = E_isa + E_rel + E_rev;
    const int nbins = (n_tot + BINW - 1) / BINW;

    char* ws = (char*)d_ws;
    auto alloc = [&](size_t bytes) -> char* {
        char* p = ws;
        ws += (bytes + 255) & ~(size_t)255;
        return p;
    };
    int* rowptr  = (int*)alloc((size_t)(n_tot + 1) * 4);
    int* col     = (int*)alloc((size_t)E_tot * 4 + 64);   // +64B slack
    int* temp    = (int*)alloc((size_t)nbins * BSLOT * 4);
    int* bin_cur = (int*)alloc((size_t)nbins * 16 * 4);   // 64B-strided counters
    int* bin_base= (int*)alloc((size_t)(nbins + 1) * 4);
    short* whi = (short*)alloc((size_t)15 * H * H * sizeof(short));
    short* wlo = (short*)alloc((size_t)15 * H * H * sizeof(short));
    _Float16* xpm[2], *xgm[2];
    xpm[0] = (_Float16*)alloc((size_t)NP * H * sizeof(_Float16));
    xpm[1] = (_Float16*)alloc((size_t)NP * H * sizeof(_Float16));
    xgm[0] = (_Float16*)alloc((size_t)NG * H * sizeof(_Float16));
    xgm[1] = (_Float16*)alloc((size_t)NG * H * sizeof(_Float16));
    short* xph = (short*)alloc((size_t)NP * H * sizeof(short));
    short* xpl = (short*)alloc((size_t)NP * H * sizeof(short));
    short* xgh = (short*)alloc((size_t)NG * H * sizeof(short));
    short* xgl = (short*)alloc((size_t)NG * H * sizeof(short));

    // ---- combined front-end: CSR scatter + W pack + layer-0 fp16 mirrors ----
    hipMemsetAsync(bin_cur, 0, (size_t)nbins * 16 * 4, stream);
    ComboArgs c;
    c.e0 = e_isa; c.E0 = E_isa; c.e1 = e_rel; c.E1 = E_rel; c.e2 = e_rev; c.E2 = E_rev;
    c.bin_cur = bin_cur; c.temp = temp; c.NPn = NP; c.NGn = NG;
    c.nbins = nbins; c.E_tot = E_tot;
    c.nbs = (E_tot + KEDGE - 1) / KEDGE;
    for (int l = 0; l < 3; ++l) {
        c.src.a[l * 5 + 0] = Wl_isa + (size_t)l * H * H;  c.src.b[l * 5 + 0] = nullptr;
        c.src.a[l * 5 + 1] = Wl_rev + (size_t)l * H * H;  c.src.b[l * 5 + 1] = nullptr;
        c.src.a[l * 5 + 2] = Wr_isa + (size_t)l * H * H;  c.src.b[l * 5 + 2] = Wr_rev + (size_t)l * H * H;
        c.src.a[l * 5 + 3] = Wl_rel + (size_t)l * H * H;  c.src.b[l * 5 + 3] = nullptr;
        c.src.a[l * 5 + 4] = Wr_rel + (size_t)l * H * H;  c.src.b[l * 5 + 4] = nullptr;
    }
    c.whi = whi; c.wlo = wlo;
    c.xa = x_pheno; c.n4a = NP * 32; c.xb = x_gene; c.n4b = NG * 32;
    c.ya = xpm[0]; c.yb = xgm[0];
    const int nb_cvt = (NP * 32 + NG * 32 + 255) / 256;
    combo_kernel<<<c.nbs + NB_PACK + nb_cvt, 256, 0, stream>>>(c);

    scan_bins<<<1, 1024, 0, stream>>>(bin_cur, nbins, bin_base);
    bin_sort_kernel<<<nbins, 256, 0, stream>>>(bin_base, temp, col, rowptr, n_tot, nbins);

    // ---- 3 fused layers (one launch each; p blocks lead, g blocks backfill) ----
    const short *pph = nullptr, *ppl = nullptr, *pgh = nullptr, *pgl = nullptr;
    const int nbp = (NP + 63) / 64, nbg = (NG + 63) / 64;
    for (int l = 0; l < 3; ++l) {
        int rs = l & 1;
        int wsid = rs ^ 1;
        LayerArgs a;
        a.p0 = GTerm{xpm[rs], 0, nullptr, nullptr, nullptr};
        a.p1 = GTerm{xgm[rs], NP + NG, nullptr, nullptr, nullptr};
        a.p2 = GTerm{nullptr, 0, pph, ppl, l == 0 ? x_pheno : nullptr};
        a.g0 = GTerm{xpm[rs], NP, nullptr, nullptr, nullptr};
        a.g1 = GTerm{nullptr, 0, pgh, pgl, l == 0 ? x_gene : nullptr};
        a.rowptr = rowptr; a.col = col; a.whi = whi; a.wlo = wlo;
        a.pm0 = l * 5 + 0; a.pm1 = l * 5 + 1; a.pm2 = l * 5 + 2;
        a.gm0 = l * 5 + 3; a.gm1 = l * 5 + 4;
        a.pb0 = bl_isa + (size_t)l * H; a.pb1 = bl_rev + (size_t)l * H;
        a.gb0 = bl_rel + (size_t)l * H;
        a.pout16 = xpm[wsid]; a.poh = xph; a.pol = xpl; a.np = NP;
        a.gout16 = xgm[wsid]; a.goh = xgh; a.gol = xgl; a.ng = NG;
        a.relu = (l < 2) ? 1 : 0; a.nbp = nbp;
        fused_layer<<<nbp + nbg, 512, 0, stream>>>(a);
        pph = xph; ppl = xpl; pgh = xgh; pgl = xgl;
    }

    // ---- decoder (layer 2 wrote mirror set 1) ----
    scores_kernel<<<(E_lbl + 15) / 16, 256, 0, stream>>>(xpm[1], xgm[1], e_lbl, E_lbl,
                                                         (float*)d_out);
}